// Round 2
// baseline (842.626 us; speedup 1.0000x reference)
//
#include <hip/hip_runtime.h>
#include <hip/hip_bf16.h>
#include <stdint.h>
#include <math.h>

#define NTOK 4096   // B*T
#define DDIM 1024
#define FDIM 4096
#define NEXP 8
#define NPAIR 8192  // NTOK * TOP_K

#define RT_TPW 8
#define RT_BLOCKS (NTOK / (4 * RT_TPW))   // 128

using short8 = __attribute__((ext_vector_type(8))) short;
using f32x4  = __attribute__((ext_vector_type(4))) float;

__device__ __forceinline__ uint16_t f2bf(float f) {
    union { float f; uint32_t u; } v; v.f = f;
    uint32_t r = v.u + 0x7FFFu + ((v.u >> 16) & 1u);   // RNE
    return (uint16_t)(r >> 16);
}

// async global->LDS, 16B per lane; LDS dest = wave-uniform base + lane*16
__device__ __forceinline__ void async16(const void* g, void* l) {
    __builtin_amdgcn_global_load_lds((const __attribute__((address_space(1))) void*)g,
                                     (__attribute__((address_space(3))) void*)l,
                                     16, 0, 0);
}

// ---------------- router ----------------
__global__ void router_kernel(const float* __restrict__ x, const float* __restrict__ Wr,
                              int* __restrict__ cnt_part, float* __restrict__ us_part,
                              int* __restrict__ top_e, float* __restrict__ top_w) {
    __shared__ float us[NEXP];
    __shared__ int cs[NEXP];
    const int tid = threadIdx.x;
    const int wv = tid >> 6;
    const int lane = tid & 63;
    if (tid < NEXP) { us[tid] = 0.f; cs[tid] = 0; }
    __syncthreads();

    for (int i = 0; i < RT_TPW; i++) {
        const int t = blockIdx.x * (4 * RT_TPW) + wv * RT_TPW + i;
        float acc[NEXP];
#pragma unroll
        for (int e = 0; e < NEXP; e++) acc[e] = 0.f;
        const float* xr = x + (size_t)t * DDIM;
        for (int d = lane; d < DDIM; d += 64) {
            float xv = xr[d];
            const float* wr = Wr + (size_t)d * NEXP;
#pragma unroll
            for (int e = 0; e < NEXP; e++) acc[e] += xv * wr[e];
        }
#pragma unroll
        for (int e = 0; e < NEXP; e++) {
#pragma unroll
            for (int off = 32; off > 0; off >>= 1) acc[e] += __shfl_xor(acc[e], off, 64);
        }
        if (lane == 0) {
            int i0 = 0;
#pragma unroll
            for (int e = 1; e < NEXP; e++) if (acc[e] > acc[i0]) i0 = e;
            int i1 = -1;
#pragma unroll
            for (int e = 0; e < NEXP; e++) {
                if (e == i0) continue;
                if (i1 < 0 || acc[e] > acc[i1]) i1 = e;
            }
            float v0 = acc[i0], v1 = acc[i1];
            float e1 = __expf(v1 - v0);
            float inv = 1.f / (1.f + e1);
            top_e[t * 2 + 0] = i0; top_e[t * 2 + 1] = i1;
            top_w[t * 2 + 0] = inv; top_w[t * 2 + 1] = e1 * inv;
            atomicAdd(&cs[i0], 1);
            atomicAdd(&cs[i1], 1);
            float m = acc[0];
#pragma unroll
            for (int e = 1; e < NEXP; e++) m = fmaxf(m, acc[e]);
            float p[NEXP]; float s = 0.f;
#pragma unroll
            for (int e = 0; e < NEXP; e++) { p[e] = __expf(acc[e] - m); s += p[e]; }
            float is = 1.f / s;
#pragma unroll
            for (int e = 0; e < NEXP; e++) atomicAdd(&us[e], p[e] * is);
        }
    }
    __syncthreads();
    if (tid < NEXP) {
        cnt_part[blockIdx.x * NEXP + tid] = cs[tid];
        us_part[blockIdx.x * NEXP + tid] = us[tid];
    }
}

__global__ void finalize_kernel(const int* __restrict__ cnt_part, const float* __restrict__ us_part,
                                int* __restrict__ counts, int* __restrict__ offs,
                                float* __restrict__ out) {
    __shared__ int c[NEXP];
    __shared__ float u[NEXP];
    const int tid = threadIdx.x;
    if (tid < NEXP) {
        int csum = 0; float usum = 0.f;
        for (int b = 0; b < RT_BLOCKS; b++) {
            csum += cnt_part[b * NEXP + tid];
            usum += us_part[b * NEXP + tid];
        }
        counts[tid] = csum; c[tid] = csum; u[tid] = usum;
    }
    __syncthreads();
    if (tid == 0) {
        int s = 0; float l = 0.f;
#pragma unroll
        for (int e = 0; e < NEXP; e++) {
            offs[e] = s; s += c[e];
            float uu = u[e] * (1.f / (float)NTOK);
            l += uu * uu;
        }
        out[(size_t)NTOK * DDIM] = (float)NEXP * l;
    }
}

__global__ void xcast_kernel(const float* __restrict__ x, uint16_t* __restrict__ xb) {
    int i = blockIdx.x * 256 + threadIdx.x;
    float4 v = ((const float4*)x)[i];
    ushort4 o;
    o.x = f2bf(v.x); o.y = f2bf(v.y); o.z = f2bf(v.z); o.w = f2bf(v.w);
    ((ushort4*)xb)[i] = o;
}

// ---------------- transpose+cast: [e][R][C] fp32 -> [e][C'][R] bf16, 64x64 tiles ----------------
// sel < 0  : plain transpose, out row = input col
// sel >= 0 : interleaved gate/up layout, out row = ((c>>4)<<5) + sel + (c&15)  (sel = 0 gate, 16 up)
__global__ void transpose_cast_kernel(const float* __restrict__ in, uint16_t* __restrict__ outp,
                                      int R, int C, int sel) {
    __shared__ uint16_t tile[64 * 64];
    const int e = blockIdx.z;
    const float* src = in + (size_t)e * R * C;
    const size_t osz = (size_t)R * C * (sel < 0 ? 1 : 2);
    uint16_t* dst = outp + (size_t)e * osz;
    const int r0 = blockIdx.y * 64, c0 = blockIdx.x * 64;
    const int t = threadIdx.x;
    {
        const int rb = t >> 4;          // 0..15
        const int c4 = t & 15;          // col group of 4
#pragma unroll
        for (int i = 0; i < 4; i++) {
            const int r = rb + i * 16;
            float4 v = *(const float4*)(src + (size_t)(r0 + r) * C + c0 + c4 * 4);
            const int rc = (r >> 3);    // chunk index of r
            const int re = (r & 7);     // elem within chunk
#pragma unroll
            for (int j = 0; j < 4; j++) {
                const int c = c4 * 4 + j;
                float fv = (j == 0) ? v.x : (j == 1) ? v.y : (j == 2) ? v.z : v.w;
                tile[c * 64 + ((rc ^ (c & 7)) << 3) + re] = f2bf(fv);
            }
        }
    }
    __syncthreads();
    {
        const int cr = t >> 3;          // 0..31 (+32 on 2nd iter): output row (= input col)
        const int ch = t & 7;           // chunk of 8 elems along r
#pragma unroll
        for (int i = 0; i < 2; i++) {
            const int c = cr + i * 32;
            uint4 v = *(const uint4*)&tile[c * 64 + ((ch ^ (c & 7)) << 3)];
            const int oc = c0 + c;
            const int orow = (sel < 0) ? oc : (((oc >> 4) << 5) + sel + (oc & 15));
            *(uint4*)(dst + (size_t)orow * R + r0 + ch * 8) = v;
        }
    }
}

__global__ void scatter_kernel(const int* __restrict__ top_e, const float* __restrict__ top_w,
                               const int* __restrict__ offs, int* __restrict__ fill,
                               int* __restrict__ pair_tok, float* __restrict__ pair_w) {
    __shared__ int lcnt[NEXP];
    __shared__ int lbase[NEXP];
    const int tid = threadIdx.x;
    const int t = blockIdx.x * 256 + tid;
    if (tid < NEXP) lcnt[tid] = 0;
    __syncthreads();
    int e0 = top_e[t * 2 + 0], e1 = top_e[t * 2 + 1];
    int r0 = atomicAdd(&lcnt[e0], 1);
    int r1 = atomicAdd(&lcnt[e1], 1);
    __syncthreads();
    if (tid < NEXP) lbase[tid] = atomicAdd(&fill[tid], lcnt[tid]);
    __syncthreads();
    int p0 = offs[e0] + lbase[e0] + r0;
    int p1 = offs[e1] + lbase[e1] + r1;
    pair_tok[p0] = t; pair_w[p0] = top_w[t * 2 + 0];
    pair_tok[p1] = t; pair_w[p1] = top_w[t * 2 + 1];
}

// ---------------- pass A: h = silu(x@W1) * (x@W3) ----------------
// Tile M=512 (pairs) x N=128 (interleaved gate/up cols), BK=32. 8 waves (4x2), per-wave 128x64.
// 3-set LDS rotation (40 KiB/set = A 512x32 + B 128x32), counted vmcnt(5), raw s_barrier.
// Rationale: BM=512 halves W13t re-reads (L3-BW-bound regime, see R1 post-mortem).
__global__ __launch_bounds__(512, 2)
void expert_up_kernel(const uint16_t* __restrict__ x_bf,
                      const uint16_t* __restrict__ W13t,
                      const int* __restrict__ counts, const int* __restrict__ offs,
                      const int* __restrict__ pair_tok, uint16_t* __restrict__ h) {
    const int e = blockIdx.z, mt = blockIdx.y, bx = blockIdx.x;
    const int cntAll = counts[e];
    if (mt * 512 >= cntAll) return;
    const int cnt = min(512, cntAll - mt * 512);
    const int pairBase = offs[e] + mt * 512;

    __shared__ uint16_t smem[3 * 20480];   // 120 KiB

    const int tid = threadIdx.x;
    const int w = tid >> 6, lane = tid & 63;
    const int wr = w >> 1, wc = w & 1;          // 4x2 wave grid
    const int lr = lane & 15, q = lane >> 4;
    const int aoff = (wr * 128 + lr) * 32 + q * 8;
    const int boff = 16384 + (wc * 64 + lr) * 32 + q * 8;
    const int ldst = tid * 8;                   // elems
    const int rowid = tid >> 2, chunk = tid & 3;

    const uint16_t* asrc[4];
#pragma unroll
    for (int i = 0; i < 4; i++) {
        int tok = pair_tok[pairBase + min(i * 128 + rowid, cnt - 1)];
        asrc[i] = x_bf + (size_t)tok * DDIM + chunk * 8;
    }
    const uint16_t* bsrc = W13t + (size_t)e * 2 * FDIM * DDIM
                         + (size_t)(bx * 128 + rowid) * DDIM + chunk * 8;

#define UST(kt_, sb_) do { \
    async16(asrc[0] + (kt_) * 32, &smem[(sb_) + ldst]); \
    async16(asrc[1] + (kt_) * 32, &smem[(sb_) + 4096 + ldst]); \
    async16(asrc[2] + (kt_) * 32, &smem[(sb_) + 8192 + ldst]); \
    async16(asrc[3] + (kt_) * 32, &smem[(sb_) + 12288 + ldst]); \
    async16(bsrc + (kt_) * 32, &smem[(sb_) + 16384 + ldst]); } while (0)

    f32x4 acc[8][4];
#pragma unroll
    for (int i = 0; i < 8; i++)
#pragma unroll
        for (int j = 0; j < 4; j++) acc[i][j] = (f32x4){0.f, 0.f, 0.f, 0.f};

    UST(0, 0); UST(1, 20480);
    asm volatile("s_waitcnt vmcnt(5)" ::: "memory");
    __builtin_amdgcn_s_barrier();

    int cur = 0;
    for (int kt = 0; kt < 32; ++kt) {
        const uint16_t* A = &smem[cur];
        short8 bf[4], af[4];
#pragma unroll
        for (int ni = 0; ni < 4; ni++) bf[ni] = *(const short8*)(A + boff + ni * 512);
#pragma unroll
        for (int mi = 0; mi < 4; mi++) af[mi] = *(const short8*)(A + aoff + mi * 512);
        if (kt + 2 < 32) {
            int stg = cur + 2 * 20480; if (stg >= 3 * 20480) stg -= 3 * 20480;
            UST(kt + 2, stg);
        }
        __builtin_amdgcn_s_barrier();
        __builtin_amdgcn_s_setprio(1);
#pragma unroll
        for (int ni = 0; ni < 4; ni++)
#pragma unroll
            for (int mi = 0; mi < 4; mi++)
                acc[mi][ni] = __builtin_amdgcn_mfma_f32_16x16x32_bf16(af[mi], bf[ni], acc[mi][ni], 0, 0, 0);
        __builtin_amdgcn_s_setprio(0);
#pragma unroll
        for (int mi = 0; mi < 4; mi++) af[mi] = *(const short8*)(A + aoff + (mi + 4) * 512);
        __builtin_amdgcn_s_setprio(1);
#pragma unroll
        for (int ni = 0; ni < 4; ni++)
#pragma unroll
            for (int mi = 0; mi < 4; mi++)
                acc[mi + 4][ni] = __builtin_amdgcn_mfma_f32_16x16x32_bf16(af[mi], bf[ni], acc[mi + 4][ni], 0, 0, 0);
        __builtin_amdgcn_s_setprio(0);
        if (kt + 2 < 32)      asm volatile("s_waitcnt vmcnt(5)" ::: "memory");
        else if (kt + 1 < 32) asm volatile("s_waitcnt vmcnt(0)" ::: "memory");
        __builtin_amdgcn_s_barrier();
        cur += 20480; if (cur == 3 * 20480) cur = 0;
    }
#undef UST

    // epilogue: ni even = gate, ni odd = up; f = bx*64 + (wc*2 + ni/2)*16 + lr
#pragma unroll
    for (int mi = 0; mi < 8; mi++) {
#pragma unroll
        for (int r = 0; r < 4; r++) {
            const int rowLocal = wr * 128 + mi * 16 + q * 4 + r;
            if (rowLocal < cnt) {
                uint16_t* dst = h + (size_t)(pairBase + rowLocal) * FDIM + bx * 64 + lr;
#pragma unroll
                for (int j = 0; j < 2; j++) {
                    float g = acc[mi][2 * j][r];
                    float u = acc[mi][2 * j + 1][r];
                    float hv = (g / (1.f + __expf(-g))) * u;
                    dst[(wc * 2 + j) * 16] = f2bf(hv);
                }
            }
        }
    }
}

// ---------------- pass B: out += weight * (h @ W2) ----------------
// Tile M=256 x N=128 (BN 64->128 halves h re-reads), BK=32. 4 waves (2x2), per-wave 128x64.
// 3-set LDS rotation (24 KiB/set), counted vmcnt(6), 2 blocks/CU.
__global__ __launch_bounds__(256, 2)
void expert_down_kernel(const uint16_t* __restrict__ h, const uint16_t* __restrict__ W2t,
                        const int* __restrict__ counts, const int* __restrict__ offs,
                        const int* __restrict__ pair_tok, const float* __restrict__ pair_w,
                        float* __restrict__ out) {
    const int e = blockIdx.z, mt = blockIdx.y;
    const int n0 = blockIdx.x * 128;
    const int cntAll = counts[e];
    if (mt * 256 >= cntAll) return;
    const int cnt = min(256, cntAll - mt * 256);
    const int pairBase = offs[e] + mt * 256;

    __shared__ uint16_t smem[3 * 12288];   // 72 KiB

    const int tid = threadIdx.x;
    const int w = tid >> 6, lane = tid & 63;    // 4 waves
    const int wr = w >> 1, wc = w & 1;
    const int lr = lane & 15, q = lane >> 4;
    const int aoff = (wr * 128 + lr) * 32 + q * 8;
    const int boff = 8192 + (wc * 64 + lr) * 32 + q * 8;
    const int ldst = tid * 8;
    const int rowid = tid >> 2, chunk = tid & 3;   // rowid 0..63

    const uint16_t* asrc[4];
#pragma unroll
    for (int i = 0; i < 4; i++) {
        int pr = pairBase + min(i * 64 + rowid, cnt - 1);
        asrc[i] = h + (size_t)pr * FDIM + chunk * 8;
    }
    const uint16_t* w2p = W2t + (size_t)e * FDIM * DDIM;
    const uint16_t* bsrc0 = w2p + (size_t)(n0 + rowid) * FDIM + chunk * 8;
    const uint16_t* bsrc1 = w2p + (size_t)(n0 + 64 + rowid) * FDIM + chunk * 8;

#define DST_(kt_, sb_) do { \
    async16(asrc[0] + (kt_) * 32, &smem[(sb_) + ldst]); \
    async16(asrc[1] + (kt_) * 32, &smem[(sb_) + 2048 + ldst]); \
    async16(asrc[2] + (kt_) * 32, &smem[(sb_) + 4096 + ldst]); \
    async16(asrc[3] + (kt_) * 32, &smem[(sb_) + 6144 + ldst]); \
    async16(bsrc0 + (kt_) * 32, &smem[(sb_) + 8192 + ldst]); \
    async16(bsrc1 + (kt_) * 32, &smem[(sb_) + 10240 + ldst]); } while (0)

    f32x4 acc[8][4];
#pragma unroll
    for (int i = 0; i < 8; i++)
#pragma unroll
        for (int j = 0; j < 4; j++) acc[i][j] = (f32x4){0.f, 0.f, 0.f, 0.f};

    DST_(0, 0); DST_(1, 12288);
    asm volatile("s_waitcnt vmcnt(6)" ::: "memory");
    __builtin_amdgcn_s_barrier();

    int cur = 0;
    for (int kt = 0; kt < 128; ++kt) {
        const uint16_t* A = &smem[cur];
        short8 bf[4], af[4];
#pragma unroll
        for (int ni = 0; ni < 4; ni++) bf[ni] = *(const short8*)(A + boff + ni * 512);
#pragma unroll
        for (int mi = 0; mi < 4; mi++) af[mi] = *(const short8*)(A + aoff + mi * 512);
        if (kt + 2 < 128) {
            int stg = cur + 2 * 12288; if (stg >= 3 * 12288) stg -= 3 * 12288;
            DST_(kt + 2, stg);
        }
        __builtin_amdgcn_s_barrier();
        __builtin_amdgcn_s_setprio(1);
#pragma unroll
        for (int ni = 0; ni < 4; ni++)
#pragma unroll
            for (int mi = 0; mi < 4; mi++)
                acc[mi][ni] = __builtin_amdgcn_mfma_f32_16x16x32_bf16(af[mi], bf[ni], acc[mi][ni], 0, 0, 0);
        __builtin_amdgcn_s_setprio(0);
#pragma unroll
        for (int mi = 0; mi < 4; mi++) af[mi] = *(const short8*)(A + aoff + (mi + 4) * 512);
        __builtin_amdgcn_s_setprio(1);
#pragma unroll
        for (int ni = 0; ni < 4; ni++)
#pragma unroll
            for (int mi = 0; mi < 4; mi++)
                acc[mi + 4][ni] = __builtin_amdgcn_mfma_f32_16x16x32_bf16(af[mi], bf[ni], acc[mi + 4][ni], 0, 0, 0);
        __builtin_amdgcn_s_setprio(0);
        if (kt + 2 < 128)      asm volatile("s_waitcnt vmcnt(6)" ::: "memory");
        else if (kt + 1 < 128) asm volatile("s_waitcnt vmcnt(0)" ::: "memory");
        __builtin_amdgcn_s_barrier();
        cur += 12288; if (cur == 3 * 12288) cur = 0;
    }
#undef DST_

#pragma unroll
    for (int mi = 0; mi < 8; mi++) {
#pragma unroll
        for (int r = 0; r < 4; r++) {
            const int rowLocal = wr * 128 + mi * 16 + q * 4 + r;
            if (rowLocal < cnt) {
                int pi = pairBase + rowLocal;
                int tok = pair_tok[pi];
                float wgt = pair_w[pi];
                float* dst = out + (size_t)tok * DDIM + n0 + wc * 64 + lr;
#pragma unroll
                for (int ni = 0; ni < 4; ni++)
                    atomicAdd(&dst[ni * 16], acc[mi][ni][r] * wgt);
            }
        }
    }
}

extern "C" void kernel_launch(void* const* d_in, const int* in_sizes, int n_in,
                              void* d_out, int out_size, void* d_ws, size_t ws_size,
                              hipStream_t stream) {
    (void)in_sizes; (void)n_in; (void)ws_size;
    const float* x  = (const float*)d_in[0];
    const float* Wr = (const float*)d_in[1];
    const float* W1 = (const float*)d_in[2];
    const float* W3 = (const float*)d_in[3];
    const float* W2 = (const float*)d_in[4];
    float* out = (float*)d_out;

    char* ws = (char*)d_ws;
    size_t off = 0;
    int*      counts    = (int*)(ws + off);  off += 64;
    int*      offs      = (int*)(ws + off);  off += 64;
    int*      fill      = (int*)(ws + off);  off += 128;
    int*      top_e     = (int*)(ws + off);  off += 4 * NPAIR;
    float*    top_w     = (float*)(ws + off); off += 4 * NPAIR;
    int*      pair_tok  = (int*)(ws + off);  off += 4 * NPAIR;
    float*    pair_w    = (float*)(ws + off); off += 4 * NPAIR;
    int*      cnt_part  = (int*)(ws + off);  off += 4 * RT_BLOCKS * NEXP;
    float*    us_part   = (float*)(ws + off); off += 4 * RT_BLOCKS * NEXP;
    uint16_t* x_bf      = (uint16_t*)(ws + off); off += (size_t)2 * NTOK * DDIM;   // 8 MB
    uint16_t* h         = (uint16_t*)(ws + off); off += (size_t)2 * NPAIR * FDIM;  // 67 MB
    const size_t wBytes = (size_t)2 * NEXP * DDIM * FDIM;   // 67.1 MB per matrix (bf16)
    uint16_t* W13t = (uint16_t*)(ws + off);                 // interleaved gate/up, 2*wBytes
    uint16_t* W2t  = (uint16_t*)(ws + off + 2 * wBytes);    // total ~277 MB (verified fits R2)

    hipMemsetAsync(ws, 0, 256, stream);
    hipMemsetAsync(d_out, 0, (size_t)out_size * sizeof(float), stream);

    xcast_kernel<<<NTOK * DDIM / 1024, 256, 0, stream>>>(x, x_bf);
    router_kernel<<<RT_BLOCKS, 256, 0, stream>>>(x, Wr, cnt_part, us_part, top_e, top_w);
    finalize_kernel<<<1, 64, 0, stream>>>(cnt_part, us_part, counts, offs, out);
    scatter_kernel<<<NTOK / 256, 256, 0, stream>>>(top_e, top_w, offs, fill, pair_tok, pair_w);

    transpose_cast_kernel<<<dim3(FDIM / 64, DDIM / 64, NEXP), 256, 0, stream>>>(W1, W13t, DDIM, FDIM, 0);
    transpose_cast_kernel<<<dim3(FDIM / 64, DDIM / 64, NEXP), 256, 0, stream>>>(W3, W13t, DDIM, FDIM, 16);
    transpose_cast_kernel<<<dim3(DDIM / 64, FDIM / 64, NEXP), 256, 0, stream>>>(W2, W2t, FDIM, DDIM, -1);

    dim3 gA(2 * FDIM / 128, NTOK / 512, NEXP);   // (64, 8, 8)
    expert_up_kernel<<<gA, 512, 0, stream>>>(x_bf, W13t, counts, offs, pair_tok, h);
    dim3 gB(DDIM / 128, NTOK / 256, NEXP);       // (8, 16, 8)
    expert_down_kernel<<<gB, 256, 0, stream>>>(h, W2t, counts, offs, pair_tok, pair_w, out);
}

// Round 3
// 794.483 us; speedup vs baseline: 1.0606x; 1.0606x over previous
//
#include <hip/hip_runtime.h>
#include <hip/hip_bf16.h>
#include <stdint.h>
#include <math.h>

#define NTOK 4096   // B*T
#define DDIM 1024
#define FDIM 4096
#define NEXP 8
#define NPAIR 8192  // NTOK * TOP_K

#define RT_TPW 8
#define RT_BLOCKS (NTOK / (4 * RT_TPW))   // 128

using short8 = __attribute__((ext_vector_type(8))) short;
using f32x4  = __attribute__((ext_vector_type(4))) float;

__device__ __forceinline__ uint16_t f2bf(float f) {
    union { float f; uint32_t u; } v; v.f = f;
    uint32_t r = v.u + 0x7FFFu + ((v.u >> 16) & 1u);   // RNE
    return (uint16_t)(r >> 16);
}

// async global->LDS, 16B per lane; LDS dest = wave-uniform base + lane*16
__device__ __forceinline__ void async16(const void* g, void* l) {
    __builtin_amdgcn_global_load_lds((const __attribute__((address_space(1))) void*)g,
                                     (__attribute__((address_space(3))) void*)l,
                                     16, 0, 0);
}

// opaque ds_read_b128: compiler's waitcnt pass cannot attach LDS-aliasing
// (vmcnt-drain) dependencies; ordering is enforced manually (rule #18).
#define DSREAD(dst_, addr_, IMM_) \
    asm volatile("ds_read_b128 %0, %1 offset:" #IMM_ : "=v"(dst_) : "v"(addr_))

// ---------------- router ----------------
__global__ void router_kernel(const float* __restrict__ x, const float* __restrict__ Wr,
                              int* __restrict__ cnt_part, float* __restrict__ us_part,
                              int* __restrict__ top_e, float* __restrict__ top_w) {
    __shared__ float us[NEXP];
    __shared__ int cs[NEXP];
    const int tid = threadIdx.x;
    const int wv = tid >> 6;
    const int lane = tid & 63;
    if (tid < NEXP) { us[tid] = 0.f; cs[tid] = 0; }
    __syncthreads();

    for (int i = 0; i < RT_TPW; i++) {
        const int t = blockIdx.x * (4 * RT_TPW) + wv * RT_TPW + i;
        float acc[NEXP];
#pragma unroll
        for (int e = 0; e < NEXP; e++) acc[e] = 0.f;
        const float* xr = x + (size_t)t * DDIM;
        for (int d = lane; d < DDIM; d += 64) {
            float xv = xr[d];
            const float* wr = Wr + (size_t)d * NEXP;
#pragma unroll
            for (int e = 0; e < NEXP; e++) acc[e] += xv * wr[e];
        }
#pragma unroll
        for (int e = 0; e < NEXP; e++) {
#pragma unroll
            for (int off = 32; off > 0; off >>= 1) acc[e] += __shfl_xor(acc[e], off, 64);
        }
        if (lane == 0) {
            int i0 = 0;
#pragma unroll
            for (int e = 1; e < NEXP; e++) if (acc[e] > acc[i0]) i0 = e;
            int i1 = -1;
#pragma unroll
            for (int e = 0; e < NEXP; e++) {
                if (e == i0) continue;
                if (i1 < 0 || acc[e] > acc[i1]) i1 = e;
            }
            float v0 = acc[i0], v1 = acc[i1];
            float e1 = __expf(v1 - v0);
            float inv = 1.f / (1.f + e1);
            top_e[t * 2 + 0] = i0; top_e[t * 2 + 1] = i1;
            top_w[t * 2 + 0] = inv; top_w[t * 2 + 1] = e1 * inv;
            atomicAdd(&cs[i0], 1);
            atomicAdd(&cs[i1], 1);
            float m = acc[0];
#pragma unroll
            for (int e = 1; e < NEXP; e++) m = fmaxf(m, acc[e]);
            float p[NEXP]; float s = 0.f;
#pragma unroll
            for (int e = 0; e < NEXP; e++) { p[e] = __expf(acc[e] - m); s += p[e]; }
            float is = 1.f / s;
#pragma unroll
            for (int e = 0; e < NEXP; e++) atomicAdd(&us[e], p[e] * is);
        }
    }
    __syncthreads();
    if (tid < NEXP) {
        cnt_part[blockIdx.x * NEXP + tid] = cs[tid];
        us_part[blockIdx.x * NEXP + tid] = us[tid];
    }
}

__global__ void finalize_kernel(const int* __restrict__ cnt_part, const float* __restrict__ us_part,
                                int* __restrict__ counts, int* __restrict__ offs,
                                float* __restrict__ out) {
    __shared__ int c[NEXP];
    __shared__ float u[NEXP];
    const int tid = threadIdx.x;
    if (tid < NEXP) {
        int csum = 0; float usum = 0.f;
        for (int b = 0; b < RT_BLOCKS; b++) {
            csum += cnt_part[b * NEXP + tid];
            usum += us_part[b * NEXP + tid];
        }
        counts[tid] = csum; c[tid] = csum; u[tid] = usum;
    }
    __syncthreads();
    if (tid == 0) {
        int s = 0; float l = 0.f;
#pragma unroll
        for (int e = 0; e < NEXP; e++) {
            offs[e] = s; s += c[e];
            float uu = u[e] * (1.f / (float)NTOK);
            l += uu * uu;
        }
        out[(size_t)NTOK * DDIM] = (float)NEXP * l;
    }
}

__global__ void xcast_kernel(const float* __restrict__ x, uint16_t* __restrict__ xb) {
    int i = blockIdx.x * 256 + threadIdx.x;
    float4 v = ((const float4*)x)[i];
    ushort4 o;
    o.x = f2bf(v.x); o.y = f2bf(v.y); o.z = f2bf(v.z); o.w = f2bf(v.w);
    ((ushort4*)xb)[i] = o;
}

// ---------------- transpose+cast: [e][R][C] fp32 -> [e][C'][R] bf16, 64x64 tiles ----------------
__global__ void transpose_cast_kernel(const float* __restrict__ in, uint16_t* __restrict__ outp,
                                      int R, int C, int sel) {
    __shared__ uint16_t tile[64 * 64];
    const int e = blockIdx.z;
    const float* src = in + (size_t)e * R * C;
    const size_t osz = (size_t)R * C * (sel < 0 ? 1 : 2);
    uint16_t* dst = outp + (size_t)e * osz;
    const int r0 = blockIdx.y * 64, c0 = blockIdx.x * 64;
    const int t = threadIdx.x;
    {
        const int rb = t >> 4;          // 0..15
        const int c4 = t & 15;          // col group of 4
#pragma unroll
        for (int i = 0; i < 4; i++) {
            const int r = rb + i * 16;
            float4 v = *(const float4*)(src + (size_t)(r0 + r) * C + c0 + c4 * 4);
            const int rc = (r >> 3);
            const int re = (r & 7);
#pragma unroll
            for (int j = 0; j < 4; j++) {
                const int c = c4 * 4 + j;
                float fv = (j == 0) ? v.x : (j == 1) ? v.y : (j == 2) ? v.z : v.w;
                tile[c * 64 + ((rc ^ (c & 7)) << 3) + re] = f2bf(fv);
            }
        }
    }
    __syncthreads();
    {
        const int cr = t >> 3;
        const int ch = t & 7;
#pragma unroll
        for (int i = 0; i < 2; i++) {
            const int c = cr + i * 32;
            uint4 v = *(const uint4*)&tile[c * 64 + ((ch ^ (c & 7)) << 3)];
            const int oc = c0 + c;
            const int orow = (sel < 0) ? oc : (((oc >> 4) << 5) + sel + (oc & 15));
            *(uint4*)(dst + (size_t)orow * R + r0 + ch * 8) = v;
        }
    }
}

__global__ void scatter_kernel(const int* __restrict__ top_e, const float* __restrict__ top_w,
                               const int* __restrict__ offs, int* __restrict__ fill,
                               int* __restrict__ pair_tok, float* __restrict__ pair_w) {
    __shared__ int lcnt[NEXP];
    __shared__ int lbase[NEXP];
    const int tid = threadIdx.x;
    const int t = blockIdx.x * 256 + tid;
    if (tid < NEXP) lcnt[tid] = 0;
    __syncthreads();
    int e0 = top_e[t * 2 + 0], e1 = top_e[t * 2 + 1];
    int r0 = atomicAdd(&lcnt[e0], 1);
    int r1 = atomicAdd(&lcnt[e1], 1);
    __syncthreads();
    if (tid < NEXP) lbase[tid] = atomicAdd(&fill[tid], lcnt[tid]);
    __syncthreads();
    int p0 = offs[e0] + lbase[e0] + r0;
    int p1 = offs[e1] + lbase[e1] + r1;
    pair_tok[p0] = t; pair_w[p0] = top_w[t * 2 + 0];
    pair_tok[p1] = t; pair_w[p1] = top_w[t * 2 + 1];
}

// ---------------- pass A: h = silu(x@W1) * (x@W3) ----------------
// 256x256 tile (N = interleaved gate/up cols), BK=32, 8 waves (2x4), per-wave 128x64.
// 3-set LDS rotation (32 KiB/set, 96 KiB), stage-ahead-2, ONE raw s_barrier per K-tile.
// Fragment ds_reads are opaque asm; manual counted lgkmcnt + sched_barrier(0) (rule #18);
// counted vmcnt(4) at tile boundary (never 0 in steady state).
// Chunk swizzle (measured conflict-free): LDS row r phys chunk p holds logical p ^ ((r>>1)&3);
// applied on the global SOURCE col (rule #21), read back with qa = q ^ ((lr>>1)&3).
__global__ __launch_bounds__(512, 2)
void expert_up_kernel(const uint16_t* __restrict__ x_bf,
                      const uint16_t* __restrict__ W13t,
                      const int* __restrict__ counts, const int* __restrict__ offs,
                      const int* __restrict__ pair_tok, uint16_t* __restrict__ h) {
    const int e = blockIdx.z, mt = blockIdx.y, bx = blockIdx.x;
    const int cntAll = counts[e];
    if (mt * 256 >= cntAll) return;
    const int cnt = min(256, cntAll - mt * 256);
    const int pairBase = offs[e] + mt * 256;

    __shared__ uint16_t smem[3 * 16384];   // 3 sets x (A 8192 + B 8192 elems) = 96 KiB

    const int tid = threadIdx.x;
    const int w = tid >> 6, lane = tid & 63;
    const int wr = w >> 2, wc = w & 3;          // 2x4 wave grid, per-wave 128x64
    const int lr = lane & 15, q = lane >> 4;
    const int qa = q ^ ((lr >> 1) & 3);
    const uint32_t lds0 = (uint32_t)(uintptr_t)&smem[0];
    const uint32_t aoffB = (uint32_t)((wr * 128 + lr) * 64 + qa * 16);
    const uint32_t boffB = (uint32_t)(16384 + (wc * 64 + lr) * 64 + qa * 16);

    const int rowid = tid >> 2;
    const int q_src = (tid & 3) ^ ((tid >> 3) & 3);   // pre-swizzled source chunk

    const int tok0 = pair_tok[pairBase + min(rowid, cnt - 1)];
    const int tok1 = pair_tok[pairBase + min(128 + rowid, cnt - 1)];
    const uint16_t* asrc0 = x_bf + (size_t)tok0 * DDIM + q_src * 8;
    const uint16_t* asrc1 = x_bf + (size_t)tok1 * DDIM + q_src * 8;
    const uint16_t* bsrc0 = W13t + (size_t)e * 2 * FDIM * DDIM
                          + (size_t)(bx * 256 + rowid) * DDIM + q_src * 8;
    const uint16_t* bsrc1 = bsrc0 + (size_t)128 * DDIM;

    // stage K-tile kt_ into set at byte offset sb_ (4 x async16 per thread-block)
#define UST(kt_, sb_) do { \
    char* Lb = (char*)smem + (sb_) + tid * 16; \
    async16(asrc0 + (kt_) * 32, Lb); \
    async16(asrc1 + (kt_) * 32, Lb + 8192); \
    async16(bsrc0 + (kt_) * 32, Lb + 16384); \
    async16(bsrc1 + (kt_) * 32, Lb + 24576); } while (0)

    f32x4 acc[8][4];
#pragma unroll
    for (int i = 0; i < 8; i++)
#pragma unroll
        for (int j = 0; j < 4; j++) acc[i][j] = (f32x4){0.f, 0.f, 0.f, 0.f};

    UST(0, 0); UST(1, 32768);
    asm volatile("s_waitcnt vmcnt(4)" ::: "memory");
    __builtin_amdgcn_s_barrier();

    uint32_t rb = 0, wb = 65536;
    for (int kt = 0; kt < 32; ++kt) {
        const uint32_t aaddr = lds0 + rb + aoffB;
        const uint32_t baddr = lds0 + rb + boffB;
        short8 af0, af1, af2, af3, af4, af5, af6, af7, bf0, bf1, bf2, bf3;
        DSREAD(af0, aaddr, 0);
        DSREAD(af1, aaddr, 1024);
        DSREAD(af2, aaddr, 2048);
        DSREAD(af3, aaddr, 3072);
        DSREAD(bf0, baddr, 0);
        DSREAD(bf1, baddr, 1024);
        DSREAD(bf2, baddr, 2048);
        DSREAD(bf3, baddr, 3072);
        DSREAD(af4, aaddr, 4096);
        DSREAD(af5, aaddr, 5120);
        DSREAD(af6, aaddr, 6144);
        DSREAD(af7, aaddr, 7168);
        if (kt < 30) UST(kt + 2, wb);
        asm volatile("s_waitcnt lgkmcnt(4)" ::: "memory");
        __builtin_amdgcn_sched_barrier(0);
        __builtin_amdgcn_s_setprio(1);
#pragma unroll
        for (int ni = 0; ni < 4; ni++) {
            const short8 bb = (ni == 0) ? bf0 : (ni == 1) ? bf1 : (ni == 2) ? bf2 : bf3;
            acc[0][ni] = __builtin_amdgcn_mfma_f32_16x16x32_bf16(af0, bb, acc[0][ni], 0, 0, 0);
            acc[1][ni] = __builtin_amdgcn_mfma_f32_16x16x32_bf16(af1, bb, acc[1][ni], 0, 0, 0);
            acc[2][ni] = __builtin_amdgcn_mfma_f32_16x16x32_bf16(af2, bb, acc[2][ni], 0, 0, 0);
            acc[3][ni] = __builtin_amdgcn_mfma_f32_16x16x32_bf16(af3, bb, acc[3][ni], 0, 0, 0);
        }
        __builtin_amdgcn_s_setprio(0);
        asm volatile("s_waitcnt lgkmcnt(0)" ::: "memory");
        __builtin_amdgcn_sched_barrier(0);
        __builtin_amdgcn_s_setprio(1);
#pragma unroll
        for (int ni = 0; ni < 4; ni++) {
            const short8 bb = (ni == 0) ? bf0 : (ni == 1) ? bf1 : (ni == 2) ? bf2 : bf3;
            acc[4][ni] = __builtin_amdgcn_mfma_f32_16x16x32_bf16(af4, bb, acc[4][ni], 0, 0, 0);
            acc[5][ni] = __builtin_amdgcn_mfma_f32_16x16x32_bf16(af5, bb, acc[5][ni], 0, 0, 0);
            acc[6][ni] = __builtin_amdgcn_mfma_f32_16x16x32_bf16(af6, bb, acc[6][ni], 0, 0, 0);
            acc[7][ni] = __builtin_amdgcn_mfma_f32_16x16x32_bf16(af7, bb, acc[7][ni], 0, 0, 0);
        }
        __builtin_amdgcn_s_setprio(0);
        if (kt < 30)       asm volatile("s_waitcnt vmcnt(4)" ::: "memory");
        else if (kt == 30) asm volatile("s_waitcnt vmcnt(0)" ::: "memory");
        __builtin_amdgcn_s_barrier();
        rb += 32768; if (rb == 98304) rb = 0;
        wb += 32768; if (wb == 98304) wb = 0;
    }
#undef UST

    // epilogue: ni even = gate, ni odd = up; f = bx*128 + (wc*2 + j)*16 + lr
#pragma unroll
    for (int mi = 0; mi < 8; mi++) {
#pragma unroll
        for (int r = 0; r < 4; r++) {
            const int rowLocal = wr * 128 + mi * 16 + q * 4 + r;
            if (rowLocal < cnt) {
                uint16_t* dst = h + (size_t)(pairBase + rowLocal) * FDIM + bx * 128 + lr;
#pragma unroll
                for (int j = 0; j < 2; j++) {
                    float g = acc[mi][2 * j][r];
                    float u = acc[mi][2 * j + 1][r];
                    float hv = (g / (1.f + __expf(-g))) * u;
                    dst[(wc * 2 + j) * 16] = f2bf(hv);
                }
            }
        }
    }
}

// ---------------- pass B: out += weight * (h @ W2) ----------------
// 256x128 tile, BK=32, 4 waves (2x2), per-wave 128x64. 3-set rotation (24 KiB/set, 72 KiB)
// -> 2 blocks/CU. Same opaque-asm / counted-wait discipline as pass A.
__global__ __launch_bounds__(256, 2)
void expert_down_kernel(const uint16_t* __restrict__ h, const uint16_t* __restrict__ W2t,
                        const int* __restrict__ counts, const int* __restrict__ offs,
                        const int* __restrict__ pair_tok, const float* __restrict__ pair_w,
                        float* __restrict__ out) {
    const int e = blockIdx.z, mt = blockIdx.y;
    const int n0 = blockIdx.x * 128;
    const int cntAll = counts[e];
    if (mt * 256 >= cntAll) return;
    const int cnt = min(256, cntAll - mt * 256);
    const int pairBase = offs[e] + mt * 256;

    __shared__ uint16_t smem[3 * 12288];   // 3 sets x (A 8192 + B 4096 elems) = 72 KiB

    const int tid = threadIdx.x;
    const int w = tid >> 6, lane = tid & 63;
    const int wr = w >> 1, wc = w & 1;          // 2x2 wave grid
    const int lr = lane & 15, q = lane >> 4;
    const int qa = q ^ ((lr >> 1) & 3);
    const uint32_t lds0 = (uint32_t)(uintptr_t)&smem[0];
    const uint32_t aoffB = (uint32_t)((wr * 128 + lr) * 64 + qa * 16);
    const uint32_t boffB = (uint32_t)(16384 + (wc * 64 + lr) * 64 + qa * 16);

    const int rowid = tid >> 2;                 // 0..63
    const int q_src = (tid & 3) ^ ((tid >> 3) & 3);

    const uint16_t* asrc[4];
#pragma unroll
    for (int i = 0; i < 4; i++) {
        int pr = pairBase + min(i * 64 + rowid, cnt - 1);
        asrc[i] = h + (size_t)pr * FDIM + q_src * 8;
    }
    const uint16_t* w2p = W2t + (size_t)e * FDIM * DDIM;
    const uint16_t* bsrc0 = w2p + (size_t)(n0 + rowid) * FDIM + q_src * 8;
    const uint16_t* bsrc1 = bsrc0 + (size_t)64 * FDIM;

#define DST_(kt_, sb_) do { \
    char* Lb = (char*)smem + (sb_) + tid * 16; \
    async16(asrc[0] + (kt_) * 32, Lb); \
    async16(asrc[1] + (kt_) * 32, Lb + 4096); \
    async16(asrc[2] + (kt_) * 32, Lb + 8192); \
    async16(asrc[3] + (kt_) * 32, Lb + 12288); \
    async16(bsrc0 + (kt_) * 32, Lb + 16384); \
    async16(bsrc1 + (kt_) * 32, Lb + 20480); } while (0)

    f32x4 acc[8][4];
#pragma unroll
    for (int i = 0; i < 8; i++)
#pragma unroll
        for (int j = 0; j < 4; j++) acc[i][j] = (f32x4){0.f, 0.f, 0.f, 0.f};

    DST_(0, 0); DST_(1, 24576);
    asm volatile("s_waitcnt vmcnt(6)" ::: "memory");
    __builtin_amdgcn_s_barrier();

    uint32_t rb = 0, wb = 49152;
    for (int kt = 0; kt < 128; ++kt) {
        const uint32_t aaddr = lds0 + rb + aoffB;
        const uint32_t baddr = lds0 + rb + boffB;
        short8 af0, af1, af2, af3, af4, af5, af6, af7, bf0, bf1, bf2, bf3;
        DSREAD(af0, aaddr, 0);
        DSREAD(af1, aaddr, 1024);
        DSREAD(af2, aaddr, 2048);
        DSREAD(af3, aaddr, 3072);
        DSREAD(bf0, baddr, 0);
        DSREAD(bf1, baddr, 1024);
        DSREAD(bf2, baddr, 2048);
        DSREAD(bf3, baddr, 3072);
        DSREAD(af4, aaddr, 4096);
        DSREAD(af5, aaddr, 5120);
        DSREAD(af6, aaddr, 6144);
        DSREAD(af7, aaddr, 7168);
        if (kt < 126) DST_(kt + 2, wb);
        asm volatile("s_waitcnt lgkmcnt(4)" ::: "memory");
        __builtin_amdgcn_sched_barrier(0);
        __builtin_amdgcn_s_setprio(1);
#pragma unroll
        for (int ni = 0; ni < 4; ni++) {
            const short8 bb = (ni == 0) ? bf0 : (ni == 1) ? bf1 : (ni == 2) ? bf2 : bf3;
            acc[0][ni] = __builtin_amdgcn_mfma_f32_16x16x32_bf16(af0, bb, acc[0][ni], 0, 0, 0);
            acc[1][ni] = __builtin_amdgcn_mfma_f32_16x16x32_bf16(af1, bb, acc[1][ni], 0, 0, 0);
            acc[2][ni] = __builtin_amdgcn_mfma_f32_16x16x32_bf16(af2, bb, acc[2][ni], 0, 0, 0);
            acc[3][ni] = __builtin_amdgcn_mfma_f32_16x16x32_bf16(af3, bb, acc[3][ni], 0, 0, 0);
        }
        __builtin_amdgcn_s_setprio(0);
        asm volatile("s_waitcnt lgkmcnt(0)" ::: "memory");
        __builtin_amdgcn_sched_barrier(0);
        __builtin_amdgcn_s_setprio(1);
#pragma unroll
        for (int ni = 0; ni < 4; ni++) {
            const short8 bb = (ni == 0) ? bf0 : (ni == 1) ? bf1 : (ni == 2) ? bf2 : bf3;
            acc[4][ni] = __builtin_amdgcn_mfma_f32_16x16x32_bf16(af4, bb, acc[4][ni], 0, 0, 0);
            acc[5][ni] = __builtin_amdgcn_mfma_f32_16x16x32_bf16(af5, bb, acc[5][ni], 0, 0, 0);
            acc[6][ni] = __builtin_amdgcn_mfma_f32_16x16x32_bf16(af6, bb, acc[6][ni], 0, 0, 0);
            acc[7][ni] = __builtin_amdgcn_mfma_f32_16x16x32_bf16(af7, bb, acc[7][ni], 0, 0, 0);
        }
        __builtin_amdgcn_s_setprio(0);
        if (kt < 126)       asm volatile("s_waitcnt vmcnt(6)" ::: "memory");
        else if (kt == 126) asm volatile("s_waitcnt vmcnt(0)" ::: "memory");
        __builtin_amdgcn_s_barrier();
        rb += 24576; if (rb == 73728) rb = 0;
        wb += 24576; if (wb == 73728) wb = 0;
    }
#undef DST_

#pragma unroll
    for (int mi = 0; mi < 8; mi++) {
#pragma unroll
        for (int r = 0; r < 4; r++) {
            const int rowLocal = wr * 128 + mi * 16 + q * 4 + r;
            if (rowLocal < cnt) {
                int pi = pairBase + rowLocal;
                int tok = pair_tok[pi];
                float wgt = pair_w[pi];
                float* dst = out + (size_t)tok * DDIM + n0 + wc * 64 + lr;
#pragma unroll
                for (int ni = 0; ni < 4; ni++)
                    atomicAdd(&dst[ni * 16], acc[mi][ni][r] * wgt);
            }
        }
    }
}

extern "C" void kernel_launch(void* const* d_in, const int* in_sizes, int n_in,
                              void* d_out, int out_size, void* d_ws, size_t ws_size,
                              hipStream_t stream) {
    (void)in_sizes; (void)n_in; (void)ws_size;
    const float* x  = (const float*)d_in[0];
    const float* Wr = (const float*)d_in[1];
    const float* W1 = (const float*)d_in[2];
    const float* W3 = (const float*)d_in[3];
    const float* W2 = (const float*)d_in[4];
    float* out = (float*)d_out;

    char* ws = (char*)d_ws;
    size_t off = 0;
    int*      counts    = (int*)(ws + off);  off += 64;
    int*      offs      = (int*)(ws + off);  off += 64;
    int*      fill      = (int*)(ws + off);  off += 128;
    int*      top_e     = (int*)(ws + off);  off += 4 * NPAIR;
    float*    top_w     = (float*)(ws + off); off += 4 * NPAIR;
    int*      pair_tok  = (int*)(ws + off);  off += 4 * NPAIR;
    float*    pair_w    = (float*)(ws + off); off += 4 * NPAIR;
    int*      cnt_part  = (int*)(ws + off);  off += 4 * RT_BLOCKS * NEXP;
    float*    us_part   = (float*)(ws + off); off += 4 * RT_BLOCKS * NEXP;
    uint16_t* x_bf      = (uint16_t*)(ws + off); off += (size_t)2 * NTOK * DDIM;   // 8 MB
    uint16_t* h         = (uint16_t*)(ws + off); off += (size_t)2 * NPAIR * FDIM;  // 67 MB
    const size_t wBytes = (size_t)2 * NEXP * DDIM * FDIM;   // 67.1 MB per matrix (bf16)
    uint16_t* W13t = (uint16_t*)(ws + off);                 // interleaved gate/up, 2*wBytes
    uint16_t* W2t  = (uint16_t*)(ws + off + 2 * wBytes);    // total ~277 MB (verified fits)

    hipMemsetAsync(ws, 0, 256, stream);
    hipMemsetAsync(d_out, 0, (size_t)out_size * sizeof(float), stream);

    xcast_kernel<<<NTOK * DDIM / 1024, 256, 0, stream>>>(x, x_bf);
    router_kernel<<<RT_BLOCKS, 256, 0, stream>>>(x, Wr, cnt_part, us_part, top_e, top_w);
    finalize_kernel<<<1, 64, 0, stream>>>(cnt_part, us_part, counts, offs, out);
    scatter_kernel<<<NTOK / 256, 256, 0, stream>>>(top_e, top_w, offs, fill, pair_tok, pair_w);

    transpose_cast_kernel<<<dim3(FDIM / 64, DDIM / 64, NEXP), 256, 0, stream>>>(W1, W13t, DDIM, FDIM, 0);
    transpose_cast_kernel<<<dim3(FDIM / 64, DDIM / 64, NEXP), 256, 0, stream>>>(W3, W13t, DDIM, FDIM, 16);
    transpose_cast_kernel<<<dim3(DDIM / 64, FDIM / 64, NEXP), 256, 0, stream>>>(W2, W2t, FDIM, DDIM, -1);

    dim3 gA(2 * FDIM / 256, NTOK / 256, NEXP);   // (32, 16, 8)
    expert_up_kernel<<<gA, 512, 0, stream>>>(x_bf, W13t, counts, offs, pair_tok, h);
    dim3 gB(DDIM / 128, NTOK / 256, NEXP);       // (8, 16, 8)
    expert_down_kernel<<<gB, 256, 0, stream>>>(h, W2t, counts, offs, pair_tok, pair_w, out);
}